// Round 6
// baseline (276.603 us; speedup 1.0000x reference)
//
#include <hip/hip_runtime.h>

#define B_SZ 4
#define IN_CH 64
#define OUT_CH 128
#define NHI 163842
#define NLO 40962
#define EPS_GN 1e-5f
#define SLOPE 0.2f

typedef __attribute__((ext_vector_type(8))) short short8;
typedef __attribute__((ext_vector_type(16))) float f32x16;

__device__ inline ushort f2bf(float f) {
    union { float f; unsigned u; } v; v.f = f;
    unsigned r = v.u + 0x7FFF + ((v.u >> 16) & 1);
    return (ushort)(r >> 16);
}
__device__ inline float bf2f(ushort h) {
    union { unsigned u; float f; } v; v.u = ((unsigned)h) << 16;
    return v.f;
}

// async global->LDS, 16B per lane; LDS dest = uniform base + lane*16
__device__ inline void glds16(const ushort* g, ushort* l) {
    typedef __attribute__((address_space(1))) const void gv;
    typedef __attribute__((address_space(3))) void lv;
    __builtin_amdgcn_global_load_lds((gv*)g, (lv*)l, 16, 0, 0);
}

// ---------------------------------------------------------------------------
// 1) Transpose x: (B,64,NHI) f32 -> xT (B,NHI,64) bf16
// ---------------------------------------------------------------------------
__global__ void k_transpose_x(const float* __restrict__ x, ushort* __restrict__ xT) {
    __shared__ float t[64][65];
    const int b   = blockIdx.y;
    const int n0  = blockIdx.x * 64;
    const int tid = threadIdx.x;
    const int nq  = tid & 15;
    const int c0  = tid >> 4;
    const bool full = (n0 + 64) <= NHI;
    if (full) {
#pragma unroll
        for (int r = 0; r < 4; ++r) {
            int c = c0 + r * 16;
            float4 v = *(const float4*)&x[((long)b * IN_CH + c) * NHI + n0 + nq * 4];
            t[c][nq * 4 + 0] = v.x; t[c][nq * 4 + 1] = v.y;
            t[c][nq * 4 + 2] = v.z; t[c][nq * 4 + 3] = v.w;
        }
    } else {
        for (int r = 0; r < 4; ++r) {
            int c = c0 + r * 16;
            for (int e = 0; e < 4; ++e) {
                int n = n0 + nq * 4 + e;
                t[c][nq * 4 + e] = (n < NHI) ? x[((long)b * IN_CH + c) * NHI + n] : 0.f;
            }
        }
    }
    __syncthreads();
    const int n  = tid >> 2;
    const int cc = (tid & 3) * 16;
    if (n0 + n < NHI) {
        short8 o0, o1;
#pragma unroll
        for (int e = 0; e < 8; ++e) {
            o0[e] = (short)f2bf(t[cc + e][n]);
            o1[e] = (short)f2bf(t[cc + 8 + e][n]);
        }
        ushort* p = &xT[((long)b * NHI + n0 + n) * 64 + cc];
        *(short8*)p = o0;
        *(short8*)(p + 8) = o1;
    }
}

// ---------------------------------------------------------------------------
// 2) Pre-tile weights W (O=128, K) f32 -> Wb bf16:
//    Wb[step][kg(8)][o(128)][e(8)],  k = step*64 + kg*8 + e
// ---------------------------------------------------------------------------
__global__ void k_prep_w(const float* __restrict__ W, ushort* __restrict__ Wb, int K) {
    int i = blockIdx.x * 256 + threadIdx.x;
    if (i >= K * 128) return;
    int k = i / 128, o = i % 128;
    int step = k >> 6, kk = k & 63, kg = kk >> 3, e = kk & 7;
    Wb[(((long)(step * 8 + kg) * 128 + o) * 8) + e] = f2bf(W[(long)o * K + k]);
}

// ---------------------------------------------------------------------------
// 3) Mean pool
// ---------------------------------------------------------------------------
__global__ void k_pool(const ushort* __restrict__ xT, const int* __restrict__ pn,
                       ushort* __restrict__ h1) {
    long t = (long)blockIdx.x * 256 + threadIdx.x;
    const long total = (long)B_SZ * NLO * 8;
    if (t >= total) return;
    int  cq = (int)(t & 7);
    long bn = t >> 3;
    int  n  = (int)(bn % NLO);
    int  b  = (int)(bn / NLO);
    float acc[8] = {};
#pragma unroll
    for (int j = 0; j < 7; ++j) {
        int idx = pn[n * 7 + j];
        short8 v = *(const short8*)&xT[((long)b * NHI + idx) * 64 + cq * 8];
#pragma unroll
        for (int e = 0; e < 8; ++e) acc[e] += bf2f((ushort)v[e]);
    }
    short8 o;
#pragma unroll
    for (int e = 0; e < 8; ++e) o[e] = (short)f2bf(acc[e] * (1.f / 7.f));
    *(short8*)&h1[bn * 64 + cq * 8] = o;
}

// ---------------------------------------------------------------------------
// 4) MFMA one-ring conv. Block 128 nodes x 128 outs, 256 threads (4 waves,
//    wave tile 64x64). A staged via coalesced VGPR gather (2 lanes per 128B
//    row-half), B staged via global_load_lds DMA. Double-buffered LDS images
//    [kg(8)][row(128)][e(8)] (conflict-free b128 reads), ONE barrier/step.
//    Per kg per wave: 2 A + 2 B ds_reads -> 4 MFMAs (1.0 reads/MFMA).
// ---------------------------------------------------------------------------
template <int CIN>
__global__ __launch_bounds__(256, 2)
void k_conv_mfma(const ushort* __restrict__ src, const int* __restrict__ nbr,
                 const ushort* __restrict__ Wb, const float* __restrict__ bias,
                 ushort* __restrict__ out, float* __restrict__ part) {
    constexpr int NSTEP = 7 * CIN / 64;
    __shared__ ushort Asm[2][8192];     // 16KB per buffer
    __shared__ ushort Bsm[2][8192];     // 16KB per buffer
    __shared__ float  red[4][2][2];

    const int b     = blockIdx.y;
    const int n0    = blockIdx.x * 128;
    const int tid   = threadIdx.x;
    const int lane  = tid & 63;
    const int wave  = tid >> 6;          // 0..3
    const int wr    = wave >> 1, wc = wave & 1;
    const int l31   = lane & 31;
    const int khalf = lane >> 5;

    // A staging roles: thread covers chunk-pair (s_kq, s_kq+4) of 2 nodes
    const int s_nn = tid >> 2;           // 0..63
    const int s_kq = tid & 3;
    const int r0 = min(n0 + s_nn, NLO - 1);
    const int r1 = min(n0 + 64 + s_nn, NLO - 1);
    int nb0[7], nb1[7];
#pragma unroll
    for (int j = 0; j < 7; ++j) {
        nb0[j] = nbr[r0 * 7 + j];
        nb1[j] = nbr[r1 * 7 + j];
    }

    const long srcb = (long)b * NLO * CIN;
    f32x16 acc[2][2] = {};
    short8 a00, a01, a10, a11;

    // prologue: B(0) DMA, A(0) load+write, barrier
#pragma unroll
    for (int i = 0; i < 4; ++i) {
        int off = (wave * 4 + i) * 512;
        glds16(&Wb[off + lane * 8], &Bsm[0][off]);
    }
    {
        const ushort* p0 = &src[srcb + (long)nb0[0] * CIN + s_kq * 8];
        const ushort* p1 = &src[srcb + (long)nb1[0] * CIN + s_kq * 8];
        a00 = *(const short8*)p0; a01 = *(const short8*)(p0 + 32);
        a10 = *(const short8*)p1; a11 = *(const short8*)(p1 + 32);
        *(short8*)&Asm[0][(s_kq * 128 + s_nn) * 8]            = a00;
        *(short8*)&Asm[0][((s_kq + 4) * 128 + s_nn) * 8]      = a01;
        *(short8*)&Asm[0][(s_kq * 128 + 64 + s_nn) * 8]       = a10;
        *(short8*)&Asm[0][((s_kq + 4) * 128 + 64 + s_nn) * 8] = a11;
    }
    __syncthreads();

    for (int step = 0; step < NSTEP; ++step) {
        const int cur = step & 1;
        const int nxt = cur ^ 1;
        if (step + 1 < NSTEP) {
            // B DMA for next step into other buffer (in flight across MFMA)
#pragma unroll
            for (int i = 0; i < 4; ++i) {
                int off = (wave * 4 + i) * 512;
                glds16(&Wb[(long)(step + 1) * 8192 + off + lane * 8], &Bsm[nxt][off]);
            }
            // A gather loads for next step (coalesced: 2 lanes per 128B half)
            const int s  = step + 1;
            const int j  = (CIN == 64) ? s : (s >> 1);
            const int cb = (CIN == 64) ? 0 : ((s & 1) * 64);
            const ushort* p0 = &src[srcb + (long)nb0[j] * CIN + cb + s_kq * 8];
            const ushort* p1 = &src[srcb + (long)nb1[j] * CIN + cb + s_kq * 8];
            a00 = *(const short8*)p0; a01 = *(const short8*)(p0 + 32);
            a10 = *(const short8*)p1; a11 = *(const short8*)(p1 + 32);
        }
#pragma unroll
        for (int kh = 0; kh < 4; ++kh) {
            const int kg = 2 * kh + khalf;
            short8 A0 = *(const short8*)&Asm[cur][(kg * 128 + wr * 64 + l31) * 8];
            short8 A1 = *(const short8*)&Asm[cur][(kg * 128 + wr * 64 + 32 + l31) * 8];
            short8 B0 = *(const short8*)&Bsm[cur][(kg * 128 + wc * 64 + l31) * 8];
            short8 B1 = *(const short8*)&Bsm[cur][(kg * 128 + wc * 64 + 32 + l31) * 8];
            acc[0][0] = __builtin_amdgcn_mfma_f32_32x32x16_bf16(A0, B0, acc[0][0], 0, 0, 0);
            acc[0][1] = __builtin_amdgcn_mfma_f32_32x32x16_bf16(A0, B1, acc[0][1], 0, 0, 0);
            acc[1][0] = __builtin_amdgcn_mfma_f32_32x32x16_bf16(A1, B0, acc[1][0], 0, 0, 0);
            acc[1][1] = __builtin_amdgcn_mfma_f32_32x32x16_bf16(A1, B1, acc[1][1], 0, 0, 0);
        }
        if (step + 1 < NSTEP) {
            // write A(next) after MFMA cluster (T14 split: load-early/write-late)
            *(short8*)&Asm[nxt][(s_kq * 128 + s_nn) * 8]            = a00;
            *(short8*)&Asm[nxt][((s_kq + 4) * 128 + s_nn) * 8]      = a01;
            *(short8*)&Asm[nxt][(s_kq * 128 + 64 + s_nn) * 8]       = a10;
            *(short8*)&Asm[nxt][((s_kq + 4) * 128 + 64 + s_nn) * 8] = a11;
        }
        __syncthreads();   // drains B-DMA(next) + A ds_writes; orders buffers
    }

    // epilogue: bias, bf16 store, per-block GroupNorm partials
    float bia[2];
#pragma unroll
    for (int n = 0; n < 2; ++n) bia[n] = bias[wc * 64 + n * 32 + l31];
    float s[2] = {}, q[2] = {};
#pragma unroll
    for (int m = 0; m < 2; ++m)
#pragma unroll
        for (int n = 0; n < 2; ++n)
#pragma unroll
            for (int r = 0; r < 16; ++r) {
                int crow = (r & 3) + 8 * (r >> 2) + 4 * khalf;
                int row  = n0 + wr * 64 + m * 32 + crow;
                float v  = acc[m][n][r] + bia[n];
                if (row < NLO) {
                    out[((long)b * NLO + row) * 128 + wc * 64 + n * 32 + l31] = f2bf(v);
                    s[n] += v; q[n] += v * v;
                }
            }
#pragma unroll
    for (int n = 0; n < 2; ++n)
#pragma unroll
        for (int off = 32; off > 0; off >>= 1) {
            s[n] += __shfl_down(s[n], off);
            q[n] += __shfl_down(q[n], off);
        }
    if (lane == 0) {
#pragma unroll
        for (int n = 0; n < 2; ++n) { red[wave][n][0] = s[n]; red[wave][n][1] = q[n]; }
    }
    __syncthreads();
    if (tid < 8) {
        int g = tid >> 1, isq = tid & 1;          // g = wc*2 + n
        int gwc = g >> 1, gn = g & 1;
        float v = red[gwc][gn][isq] + red[2 + gwc][gn][isq];
        part[(((long)b * gridDim.x + blockIdx.x) * 4 + g) * 2 + isq] = v;
    }
}

// ---------------------------------------------------------------------------
// 5) Finalize stats -> per (b,c) scale/shift. One block per (b,g).
// ---------------------------------------------------------------------------
__global__ void k_finalize(const float* __restrict__ part, int nblk,
                           const float* __restrict__ w, const float* __restrict__ bb,
                           float* __restrict__ scale, float* __restrict__ shift) {
    const int b = blockIdx.x >> 2, g = blockIdx.x & 3;
    const int tid = threadIdx.x;
    float s = 0.f, ss = 0.f;
    for (int k = tid; k < nblk; k += 256) {
        s  += part[(((long)b * nblk + k) * 4 + g) * 2 + 0];
        ss += part[(((long)b * nblk + k) * 4 + g) * 2 + 1];
    }
#pragma unroll
    for (int off = 32; off > 0; off >>= 1) {
        s += __shfl_down(s, off); ss += __shfl_down(ss, off);
    }
    __shared__ float red[8];
    __shared__ float fin[2];
    const int wave = tid >> 6, lane = tid & 63;
    if (lane == 0) { red[wave * 2] = s; red[wave * 2 + 1] = ss; }
    __syncthreads();
    if (tid == 0) {
        float as = red[0] + red[2] + red[4] + red[6];
        float aq = red[1] + red[3] + red[5] + red[7];
        const float cnt = 32.f * NLO;
        float mu  = as / cnt;
        float var = aq / cnt - mu * mu;
        fin[0] = mu; fin[1] = rsqrtf(var + EPS_GN);
    }
    __syncthreads();
    if (tid < 32) {
        int c = g * 32 + tid;
        float sc = fin[1] * w[c];
        scale[b * 128 + c] = sc;
        shift[b * 128 + c] = bb[c] - fin[0] * sc;
    }
}

// ---------------------------------------------------------------------------
// 6) Elementwise gn+leakyrelu: y (B,NLO,128) bf16 -> yp bf16
// ---------------------------------------------------------------------------
__global__ void k_gnapply(const ushort* __restrict__ y, const float* __restrict__ sc,
                          const float* __restrict__ sh, ushort* __restrict__ yp) {
    long t = (long)blockIdx.x * 256 + threadIdx.x;
    const long total = (long)B_SZ * NLO * 16;
    if (t >= total) return;
    int  c8 = (int)(t & 15);
    long bn = t >> 4;
    int  b  = (int)(bn / NLO);
    short8 v = *(const short8*)&y[bn * 128 + c8 * 8];
    short8 o;
#pragma unroll
    for (int e = 0; e < 8; ++e) {
        int c = c8 * 8 + e;
        float f = bf2f((ushort)v[e]) * sc[b * 128 + c] + sh[b * 128 + c];
        f = fmaxf(f, SLOPE * f);
        o[e] = (short)f2bf(f);
    }
    *(short8*)&yp[bn * 128 + c8 * 8] = o;
}

// ---------------------------------------------------------------------------
// 7) Output: gn2 + leakyrelu + transpose (B,N,128) bf16 -> (B,128,N) f32
// ---------------------------------------------------------------------------
__global__ void k_output(const ushort* __restrict__ y2, const float* __restrict__ scale,
                         const float* __restrict__ shift, float* __restrict__ out) {
    __shared__ float t[32][129];
    const int b   = blockIdx.y;
    const int n0  = blockIdx.x * 32;
    const int tid = threadIdx.x;
    const float* scb = &scale[b * 128];
    const float* shb = &shift[b * 128];
    const int c8 = (tid & 15) * 8;
#pragma unroll
    for (int r = 0; r < 2; ++r) {
        int nn = (tid >> 4) + r * 16;
        int n  = n0 + nn;
        if (n < NLO) {
            short8 v = *(const short8*)&y2[((long)b * NLO + n) * 128 + c8];
#pragma unroll
            for (int e = 0; e < 8; ++e) {
                int c = c8 + e;
                float f = bf2f((ushort)v[e]) * scb[c] + shb[c];
                t[nn][c] = fmaxf(f, SLOPE * f);
            }
        } else {
#pragma unroll
            for (int e = 0; e < 8; ++e) t[nn][c8 + e] = 0.f;
        }
    }
    __syncthreads();
    const int n4 = (tid & 7) * 4;
    const bool full = (n0 + 32) <= NLO;
#pragma unroll
    for (int r = 0; r < 4; ++r) {
        int c = (tid >> 3) + r * 32;
        long o = ((long)b * 128 + c) * NLO + n0 + n4;
        if (full) {
            float2 v0 = make_float2(t[n4][c], t[n4 + 1][c]);
            float2 v1 = make_float2(t[n4 + 2][c], t[n4 + 3][c]);
            *(float2*)&out[o]     = v0;
            *(float2*)&out[o + 2] = v1;
        } else {
            for (int e = 0; e < 4; ++e)
                if (n0 + n4 + e < NLO) out[o + e] = t[n4 + e][c];
        }
    }
}

// ---------------------------------------------------------------------------
// Launch
// ---------------------------------------------------------------------------
extern "C" void kernel_launch(void* const* d_in, const int* in_sizes, int n_in,
                              void* d_out, int out_size, void* d_ws, size_t ws_size,
                              hipStream_t stream) {
    const float* x   = (const float*)d_in[0];
    const int*   pn  = (const int*)d_in[1];
    const int*   cn  = (const int*)d_in[2];
    const float* W1  = (const float*)d_in[3];
    const float* b1  = (const float*)d_in[4];
    const float* g1w = (const float*)d_in[5];
    const float* g1b = (const float*)d_in[6];
    const float* W2  = (const float*)d_in[7];
    const float* b2  = (const float*)d_in[8];
    const float* g2w = (const float*)d_in[9];
    const float* g2b = (const float*)d_in[10];
    float* out = (float*)d_out;
    char*  base = (char*)d_ws;

    ushort* xT  = (ushort*)(base + 0);           // 83,887,104 B
    ushort* y1  = (ushort*)(base + 0);           // reuse (xT dead after pool)
    ushort* y1p = (ushort*)(base + 44000000);
    ushort* h1  = (ushort*)(base + 88000000);
    ushort* y2  = (ushort*)(base + 110000000);
    ushort* wb1 = (ushort*)(base + 152000000);
    ushort* wb2 = (ushort*)(base + 152200000);
    float*  p1  = (float*)(base + 152500000);
    float*  p2  = (float*)(base + 152600000);
    float*  sc1 = (float*)(base + 152700000);
    float*  sh1 = sc1 + 512;
    float*  sc2 = (float*)(base + 152710000);
    float*  sh2 = sc2 + 512;

    const int NBLK = (NLO + 127) / 128;  // 321 conv blocks per batch

    k_transpose_x<<<dim3((NHI + 63) / 64, B_SZ), 256, 0, stream>>>(x, xT);
    k_prep_w<<<(448 * 128 + 255) / 256, 256, 0, stream>>>(W1, wb1, 448);
    k_prep_w<<<(896 * 128 + 255) / 256, 256, 0, stream>>>(W2, wb2, 896);
    k_pool<<<(int)(((long)B_SZ * NLO * 8 + 255) / 256), 256, 0, stream>>>(xT, pn, h1);
    k_conv_mfma<64><<<dim3(NBLK, B_SZ), 256, 0, stream>>>(h1, cn, wb1, b1, y1, p1);
    k_finalize<<<16, 256, 0, stream>>>(p1, NBLK, g1w, g1b, sc1, sh1);
    k_gnapply<<<(int)(((long)B_SZ * NLO * 16 + 255) / 256), 256, 0, stream>>>(y1, sc1, sh1, y1p);
    k_conv_mfma<128><<<dim3(NBLK, B_SZ), 256, 0, stream>>>(y1p, cn, wb2, b2, y2, p2);
    k_finalize<<<16, 256, 0, stream>>>(p2, NBLK, g2w, g2b, sc2, sh2);
    k_output<<<dim3((NLO + 31) / 32, B_SZ), 256, 0, stream>>>(y2, sc2, sh2, out);
}

// Round 7
// 262.392 us; speedup vs baseline: 1.0542x; 1.0542x over previous
//
#include <hip/hip_runtime.h>

#define B_SZ 4
#define IN_CH 64
#define OUT_CH 128
#define NHI 163842
#define NLO 40962
#define EPS_GN 1e-5f
#define SLOPE 0.2f

typedef __attribute__((ext_vector_type(8))) short short8;
typedef __attribute__((ext_vector_type(16))) float f32x16;

__device__ inline ushort f2bf(float f) {
    union { float f; unsigned u; } v; v.f = f;
    unsigned r = v.u + 0x7FFF + ((v.u >> 16) & 1);
    return (ushort)(r >> 16);
}
__device__ inline float bf2f(ushort h) {
    union { unsigned u; float f; } v; v.u = ((unsigned)h) << 16;
    return v.f;
}

// ---------------------------------------------------------------------------
// 1) Transpose x: (B,64,NHI) f32 -> xT (B,NHI,64) bf16
// ---------------------------------------------------------------------------
__global__ void k_transpose_x(const float* __restrict__ x, ushort* __restrict__ xT) {
    __shared__ float t[64][65];
    const int b   = blockIdx.y;
    const int n0  = blockIdx.x * 64;
    const int tid = threadIdx.x;
    const int nq  = tid & 15;
    const int c0  = tid >> 4;
    const bool full = (n0 + 64) <= NHI;
    if (full) {
#pragma unroll
        for (int r = 0; r < 4; ++r) {
            int c = c0 + r * 16;
            float4 v = *(const float4*)&x[((long)b * IN_CH + c) * NHI + n0 + nq * 4];
            t[c][nq * 4 + 0] = v.x; t[c][nq * 4 + 1] = v.y;
            t[c][nq * 4 + 2] = v.z; t[c][nq * 4 + 3] = v.w;
        }
    } else {
        for (int r = 0; r < 4; ++r) {
            int c = c0 + r * 16;
            for (int e = 0; e < 4; ++e) {
                int n = n0 + nq * 4 + e;
                t[c][nq * 4 + e] = (n < NHI) ? x[((long)b * IN_CH + c) * NHI + n] : 0.f;
            }
        }
    }
    __syncthreads();
    const int n  = tid >> 2;
    const int cc = (tid & 3) * 16;
    if (n0 + n < NHI) {
        short8 o0, o1;
#pragma unroll
        for (int e = 0; e < 8; ++e) {
            o0[e] = (short)f2bf(t[cc + e][n]);
            o1[e] = (short)f2bf(t[cc + 8 + e][n]);
        }
        ushort* p = &xT[((long)b * NHI + n0 + n) * 64 + cc];
        *(short8*)p = o0;
        *(short8*)(p + 8) = o1;
    }
}

// ---------------------------------------------------------------------------
// 2) Pre-tile weights W (O=128, K) f32 -> Wb bf16:
//    Wb[step][kg(8)][o(128)][e(8)],  k = step*64 + kg*8 + e
// ---------------------------------------------------------------------------
__global__ void k_prep_w(const float* __restrict__ W, ushort* __restrict__ Wb, int K) {
    int i = blockIdx.x * 256 + threadIdx.x;
    if (i >= K * 128) return;
    int k = i / 128, o = i % 128;
    int step = k >> 6, kk = k & 63, kg = kk >> 3, e = kk & 7;
    Wb[(((long)(step * 8 + kg) * 128 + o) * 8) + e] = f2bf(W[(long)o * K + k]);
}

// ---------------------------------------------------------------------------
// 3) Mean pool
// ---------------------------------------------------------------------------
__global__ void k_pool(const ushort* __restrict__ xT, const int* __restrict__ pn,
                       ushort* __restrict__ h1) {
    long t = (long)blockIdx.x * 256 + threadIdx.x;
    const long total = (long)B_SZ * NLO * 8;
    if (t >= total) return;
    int  cq = (int)(t & 7);
    long bn = t >> 3;
    int  n  = (int)(bn % NLO);
    int  b  = (int)(bn / NLO);
    float acc[8] = {};
#pragma unroll
    for (int j = 0; j < 7; ++j) {
        int idx = pn[n * 7 + j];
        short8 v = *(const short8*)&xT[((long)b * NHI + idx) * 64 + cq * 8];
#pragma unroll
        for (int e = 0; e < 8; ++e) acc[e] += bf2f((ushort)v[e]);
    }
    short8 o;
#pragma unroll
    for (int e = 0; e < 8; ++e) o[e] = (short)f2bf(acc[e] * (1.f / 7.f));
    *(short8*)&h1[bn * 64 + cq * 8] = o;
}

// swizzled A-image index: logical (kg, nn) -> ushort offset. XOR of kg into
// nn's low bits makes BOTH staging writes and fragment reads bank-conflict-free.
__device__ inline int aidx(int kg, int nn) {
    return (kg * 128 + (nn ^ (kg << 1))) * 8;
}

// ---------------------------------------------------------------------------
// 4) MFMA one-ring conv. Block 128 nodes x 128 outs, 256 threads (4 waves,
//    wave tile 64x64). A staged via coalesced gather -> swizzled LDS (dbuf,
//    one barrier/step). B (weights) loaded DIRECTLY global->VGPR: the
//    pre-tiled image makes each fragment a contiguous 512B wave read, and
//    all blocks read the same 229KB -> L2-resident broadcast. No B in LDS:
//    LDS = 32KB -> 3 blocks/CU (launch_bounds cap), 12 waves/CU.
// ---------------------------------------------------------------------------
template <int CIN>
__global__ __launch_bounds__(256, 3)
void k_conv_mfma(const ushort* __restrict__ src, const int* __restrict__ nbr,
                 const ushort* __restrict__ Wb, const float* __restrict__ bias,
                 ushort* __restrict__ out, float* __restrict__ part) {
    constexpr int NSTEP = 7 * CIN / 64;
    __shared__ ushort Asm[2][8192];     // 16KB per buffer, swizzled image
    __shared__ float  red[4][2][2];

    const int b     = blockIdx.y;
    const int n0    = blockIdx.x * 128;
    const int tid   = threadIdx.x;
    const int lane  = tid & 63;
    const int wave  = tid >> 6;          // 0..3
    const int wr    = wave >> 1, wc = wave & 1;
    const int l31   = lane & 31;
    const int khalf = lane >> 5;

    // A staging roles: thread covers chunk-pair (s_kq, s_kq+4) of 2 nodes
    const int s_nn = tid >> 2;           // 0..63
    const int s_kq = tid & 3;
    const int r0 = min(n0 + s_nn, NLO - 1);
    const int r1 = min(n0 + 64 + s_nn, NLO - 1);
    int nb0[7], nb1[7];
#pragma unroll
    for (int j = 0; j < 7; ++j) {
        nb0[j] = nbr[r0 * 7 + j];
        nb1[j] = nbr[r1 * 7 + j];
    }

    const long srcb = (long)b * NLO * CIN;
    f32x16 acc[2][2] = {};
    short8 a00, a01, a10, a11;

    // prologue: A(0) load+write, barrier
    {
        const ushort* p0 = &src[srcb + (long)nb0[0] * CIN + s_kq * 8];
        const ushort* p1 = &src[srcb + (long)nb1[0] * CIN + s_kq * 8];
        a00 = *(const short8*)p0; a01 = *(const short8*)(p0 + 32);
        a10 = *(const short8*)p1; a11 = *(const short8*)(p1 + 32);
        *(short8*)&Asm[0][aidx(s_kq,     s_nn)]      = a00;
        *(short8*)&Asm[0][aidx(s_kq + 4, s_nn)]      = a01;
        *(short8*)&Asm[0][aidx(s_kq,     64 + s_nn)] = a10;
        *(short8*)&Asm[0][aidx(s_kq + 4, 64 + s_nn)] = a11;
    }
    __syncthreads();

    for (int step = 0; step < NSTEP; ++step) {
        const int cur = step & 1;
        const int nxt = cur ^ 1;
        // B fragments for this step: direct global->VGPR, coalesced, L2-hot
        short8 bfr[4][2];
        {
            const ushort* wb = &Wb[(long)step * 8192 + (khalf * 128 + wc * 64 + l31) * 8];
#pragma unroll
            for (int kh = 0; kh < 4; ++kh) {
                bfr[kh][0] = *(const short8*)(wb + kh * 2 * 128 * 8);
                bfr[kh][1] = *(const short8*)(wb + kh * 2 * 128 * 8 + 32 * 8);
            }
        }
        // A gather loads for next step (coalesced: 2 lanes per 128B row-half)
        if (step + 1 < NSTEP) {
            const int s  = step + 1;
            const int j  = (CIN == 64) ? s : (s >> 1);
            const int cb = (CIN == 64) ? 0 : ((s & 1) * 64);
            const ushort* p0 = &src[srcb + (long)nb0[j] * CIN + cb + s_kq * 8];
            const ushort* p1 = &src[srcb + (long)nb1[j] * CIN + cb + s_kq * 8];
            a00 = *(const short8*)p0; a01 = *(const short8*)(p0 + 32);
            a10 = *(const short8*)p1; a11 = *(const short8*)(p1 + 32);
        }
#pragma unroll
        for (int kh = 0; kh < 4; ++kh) {
            const int kg = 2 * kh + khalf;
            short8 A0 = *(const short8*)&Asm[cur][aidx(kg, wr * 64 + l31)];
            short8 A1 = *(const short8*)&Asm[cur][aidx(kg, wr * 64 + 32 + l31)];
            acc[0][0] = __builtin_amdgcn_mfma_f32_32x32x16_bf16(A0, bfr[kh][0], acc[0][0], 0, 0, 0);
            acc[0][1] = __builtin_amdgcn_mfma_f32_32x32x16_bf16(A0, bfr[kh][1], acc[0][1], 0, 0, 0);
            acc[1][0] = __builtin_amdgcn_mfma_f32_32x32x16_bf16(A1, bfr[kh][0], acc[1][0], 0, 0, 0);
            acc[1][1] = __builtin_amdgcn_mfma_f32_32x32x16_bf16(A1, bfr[kh][1], acc[1][1], 0, 0, 0);
        }
        if (step + 1 < NSTEP) {
            // write A(next) after the MFMA cluster (load-early / write-late)
            *(short8*)&Asm[nxt][aidx(s_kq,     s_nn)]      = a00;
            *(short8*)&Asm[nxt][aidx(s_kq + 4, s_nn)]      = a01;
            *(short8*)&Asm[nxt][aidx(s_kq,     64 + s_nn)] = a10;
            *(short8*)&Asm[nxt][aidx(s_kq + 4, 64 + s_nn)] = a11;
        }
        __syncthreads();   // reads(cur) drained; writes(nxt) visible next step
    }

    // epilogue: bias, bf16 store, per-block GroupNorm partials
    float bia[2];
#pragma unroll
    for (int n = 0; n < 2; ++n) bia[n] = bias[wc * 64 + n * 32 + l31];
    float s[2] = {}, q[2] = {};
#pragma unroll
    for (int m = 0; m < 2; ++m)
#pragma unroll
        for (int n = 0; n < 2; ++n)
#pragma unroll
            for (int r = 0; r < 16; ++r) {
                int crow = (r & 3) + 8 * (r >> 2) + 4 * khalf;
                int row  = n0 + wr * 64 + m * 32 + crow;
                float v  = acc[m][n][r] + bia[n];
                if (row < NLO) {
                    out[((long)b * NLO + row) * 128 + wc * 64 + n * 32 + l31] = f2bf(v);
                    s[n] += v; q[n] += v * v;
                }
            }
#pragma unroll
    for (int n = 0; n < 2; ++n)
#pragma unroll
        for (int off = 32; off > 0; off >>= 1) {
            s[n] += __shfl_down(s[n], off);
            q[n] += __shfl_down(q[n], off);
        }
    if (lane == 0) {
#pragma unroll
        for (int n = 0; n < 2; ++n) { red[wave][n][0] = s[n]; red[wave][n][1] = q[n]; }
    }
    __syncthreads();
    if (tid < 8) {
        int g = tid >> 1, isq = tid & 1;          // g = wc*2 + n
        int gwc = g >> 1, gn = g & 1;
        float v = red[gwc][gn][isq] + red[2 + gwc][gn][isq];
        part[(((long)b * gridDim.x + blockIdx.x) * 4 + g) * 2 + isq] = v;
    }
}

// ---------------------------------------------------------------------------
// 5) Finalize stats -> per (b,c) scale/shift. One block per (b,g).
// ---------------------------------------------------------------------------
__global__ void k_finalize(const float* __restrict__ part, int nblk,
                           const float* __restrict__ w, const float* __restrict__ bb,
                           float* __restrict__ scale, float* __restrict__ shift) {
    const int b = blockIdx.x >> 2, g = blockIdx.x & 3;
    const int tid = threadIdx.x;
    float s = 0.f, ss = 0.f;
    for (int k = tid; k < nblk; k += 256) {
        s  += part[(((long)b * nblk + k) * 4 + g) * 2 + 0];
        ss += part[(((long)b * nblk + k) * 4 + g) * 2 + 1];
    }
#pragma unroll
    for (int off = 32; off > 0; off >>= 1) {
        s += __shfl_down(s, off); ss += __shfl_down(ss, off);
    }
    __shared__ float red[8];
    __shared__ float fin[2];
    const int wave = tid >> 6, lane = tid & 63;
    if (lane == 0) { red[wave * 2] = s; red[wave * 2 + 1] = ss; }
    __syncthreads();
    if (tid == 0) {
        float as = red[0] + red[2] + red[4] + red[6];
        float aq = red[1] + red[3] + red[5] + red[7];
        const float cnt = 32.f * NLO;
        float mu  = as / cnt;
        float var = aq / cnt - mu * mu;
        fin[0] = mu; fin[1] = rsqrtf(var + EPS_GN);
    }
    __syncthreads();
    if (tid < 32) {
        int c = g * 32 + tid;
        float sc = fin[1] * w[c];
        scale[b * 128 + c] = sc;
        shift[b * 128 + c] = bb[c] - fin[0] * sc;
    }
}

// ---------------------------------------------------------------------------
// 6) Elementwise gn+leakyrelu: y (B,NLO,128) bf16 -> yp bf16
// ---------------------------------------------------------------------------
__global__ void k_gnapply(const ushort* __restrict__ y, const float* __restrict__ sc,
                          const float* __restrict__ sh, ushort* __restrict__ yp) {
    long t = (long)blockIdx.x * 256 + threadIdx.x;
    const long total = (long)B_SZ * NLO * 16;
    if (t >= total) return;
    int  c8 = (int)(t & 15);
    long bn = t >> 4;
    int  b  = (int)(bn / NLO);
    short8 v = *(const short8*)&y[bn * 128 + c8 * 8];
    short8 o;
#pragma unroll
    for (int e = 0; e < 8; ++e) {
        int c = c8 * 8 + e;
        float f = bf2f((ushort)v[e]) * sc[b * 128 + c] + sh[b * 128 + c];
        f = fmaxf(f, SLOPE * f);
        o[e] = (short)f2bf(f);
    }
    *(short8*)&yp[bn * 128 + c8 * 8] = o;
}

// ---------------------------------------------------------------------------
// 7) Output: gn2 + leakyrelu + transpose (B,N,128) bf16 -> (B,128,N) f32
// ---------------------------------------------------------------------------
__global__ void k_output(const ushort* __restrict__ y2, const float* __restrict__ scale,
                         const float* __restrict__ shift, float* __restrict__ out) {
    __shared__ float t[32][129];
    const int b   = blockIdx.y;
    const int n0  = blockIdx.x * 32;
    const int tid = threadIdx.x;
    const float* scb = &scale[b * 128];
    const float* shb = &shift[b * 128];
    const int c8 = (tid & 15) * 8;
#pragma unroll
    for (int r = 0; r < 2; ++r) {
        int nn = (tid >> 4) + r * 16;
        int n  = n0 + nn;
        if (n < NLO) {
            short8 v = *(const short8*)&y2[((long)b * NLO + n) * 128 + c8];
#pragma unroll
            for (int e = 0; e < 8; ++e) {
                int c = c8 + e;
                float f = bf2f((ushort)v[e]) * scb[c] + shb[c];
                t[nn][c] = fmaxf(f, SLOPE * f);
            }
        } else {
#pragma unroll
            for (int e = 0; e < 8; ++e) t[nn][c8 + e] = 0.f;
        }
    }
    __syncthreads();
    const int n4 = (tid & 7) * 4;
    const bool full = (n0 + 32) <= NLO;
#pragma unroll
    for (int r = 0; r < 4; ++r) {
        int c = (tid >> 3) + r * 32;
        long o = ((long)b * 128 + c) * NLO + n0 + n4;
        if (full) {
            float2 v0 = make_float2(t[n4][c], t[n4 + 1][c]);
            float2 v1 = make_float2(t[n4 + 2][c], t[n4 + 3][c]);
            *(float2*)&out[o]     = v0;
            *(float2*)&out[o + 2] = v1;
        } else {
            for (int e = 0; e < 4; ++e)
                if (n0 + n4 + e < NLO) out[o + e] = t[n4 + e][c];
        }
    }
}

// ---------------------------------------------------------------------------
// Launch
// ---------------------------------------------------------------------------
extern "C" void kernel_launch(void* const* d_in, const int* in_sizes, int n_in,
                              void* d_out, int out_size, void* d_ws, size_t ws_size,
                              hipStream_t stream) {
    const float* x   = (const float*)d_in[0];
    const int*   pn  = (const int*)d_in[1];
    const int*   cn  = (const int*)d_in[2];
    const float* W1  = (const float*)d_in[3];
    const float* b1  = (const float*)d_in[4];
    const float* g1w = (const float*)d_in[5];
    const float* g1b = (const float*)d_in[6];
    const float* W2  = (const float*)d_in[7];
    const float* b2  = (const float*)d_in[8];
    const float* g2w = (const float*)d_in[9];
    const float* g2b = (const float*)d_in[10];
    float* out = (float*)d_out;
    char*  base = (char*)d_ws;

    ushort* xT  = (ushort*)(base + 0);           // 83,887,104 B
    ushort* y1  = (ushort*)(base + 0);           // reuse (xT dead after pool)
    ushort* y1p = (ushort*)(base + 44000000);
    ushort* h1  = (ushort*)(base + 88000000);
    ushort* y2  = (ushort*)(base + 110000000);
    ushort* wb1 = (ushort*)(base + 152000000);
    ushort* wb2 = (ushort*)(base + 152200000);
    float*  p1  = (float*)(base + 152500000);
    float*  p2  = (float*)(base + 152600000);
    float*  sc1 = (float*)(base + 152700000);
    float*  sh1 = sc1 + 512;
    float*  sc2 = (float*)(base + 152710000);
    float*  sh2 = sc2 + 512;

    const int NBLK = (NLO + 127) / 128;  // 321 conv blocks per batch

    k_transpose_x<<<dim3((NHI + 63) / 64, B_SZ), 256, 0, stream>>>(x, xT);
    k_prep_w<<<(448 * 128 + 255) / 256, 256, 0, stream>>>(W1, wb1, 448);
    k_prep_w<<<(896 * 128 + 255) / 256, 256, 0, stream>>>(W2, wb2, 896);
    k_pool<<<(int)(((long)B_SZ * NLO * 8 + 255) / 256), 256, 0, stream>>>(xT, pn, h1);
    k_conv_mfma<64><<<dim3(NBLK, B_SZ), 256, 0, stream>>>(h1, cn, wb1, b1, y1, p1);
    k_finalize<<<16, 256, 0, stream>>>(p1, NBLK, g1w, g1b, sc1, sh1);
    k_gnapply<<<(int)(((long)B_SZ * NLO * 16 + 255) / 256), 256, 0, stream>>>(y1, sc1, sh1, y1p);
    k_conv_mfma<128><<<dim3(NBLK, B_SZ), 256, 0, stream>>>(y1p, cn, wb2, b2, y2, p2);
    k_finalize<<<16, 256, 0, stream>>>(p2, NBLK, g2w, g2b, sc2, sh2);
    k_output<<<dim3((NLO + 31) / 32, B_SZ), 256, 0, stream>>>(y2, sc2, sh2, out);
}

// Round 8
// 258.865 us; speedup vs baseline: 1.0685x; 1.0136x over previous
//
#include <hip/hip_runtime.h>

#define B_SZ 4
#define IN_CH 64
#define OUT_CH 128
#define NHI 163842
#define NLO 40962
#define EPS_GN 1e-5f
#define SLOPE 0.2f

typedef __attribute__((ext_vector_type(8))) short short8;
typedef __attribute__((ext_vector_type(16))) float f32x16;

__device__ inline ushort f2bf(float f) {
    union { float f; unsigned u; } v; v.f = f;
    unsigned r = v.u + 0x7FFF + ((v.u >> 16) & 1);
    return (ushort)(r >> 16);
}
__device__ inline float bf2f(ushort h) {
    union { unsigned u; float f; } v; v.u = ((unsigned)h) << 16;
    return v.f;
}

// ---------------------------------------------------------------------------
// 1) Transpose x: (B,64,NHI) f32 -> xT (B,NHI,64) bf16
// ---------------------------------------------------------------------------
__global__ void k_transpose_x(const float* __restrict__ x, ushort* __restrict__ xT) {
    __shared__ float t[64][65];
    const int b   = blockIdx.y;
    const int n0  = blockIdx.x * 64;
    const int tid = threadIdx.x;
    const int nq  = tid & 15;
    const int c0  = tid >> 4;
    const bool full = (n0 + 64) <= NHI;
    if (full) {
#pragma unroll
        for (int r = 0; r < 4; ++r) {
            int c = c0 + r * 16;
            float4 v = *(const float4*)&x[((long)b * IN_CH + c) * NHI + n0 + nq * 4];
            t[c][nq * 4 + 0] = v.x; t[c][nq * 4 + 1] = v.y;
            t[c][nq * 4 + 2] = v.z; t[c][nq * 4 + 3] = v.w;
        }
    } else {
        for (int r = 0; r < 4; ++r) {
            int c = c0 + r * 16;
            for (int e = 0; e < 4; ++e) {
                int n = n0 + nq * 4 + e;
                t[c][nq * 4 + e] = (n < NHI) ? x[((long)b * IN_CH + c) * NHI + n] : 0.f;
            }
        }
    }
    __syncthreads();
    const int n  = tid >> 2;
    const int cc = (tid & 3) * 16;
    if (n0 + n < NHI) {
        short8 o0, o1;
#pragma unroll
        for (int e = 0; e < 8; ++e) {
            o0[e] = (short)f2bf(t[cc + e][n]);
            o1[e] = (short)f2bf(t[cc + 8 + e][n]);
        }
        ushort* p = &xT[((long)b * NHI + n0 + n) * 64 + cc];
        *(short8*)p = o0;
        *(short8*)(p + 8) = o1;
    }
}

// ---------------------------------------------------------------------------
// 2) Pre-tile weights W (O=128, K) f32 -> Wb bf16:
//    Wb[kglobal(=j*KG+kg)][o(128)][e(8)],  k = kglobal*8 + e
// ---------------------------------------------------------------------------
__global__ void k_prep_w(const float* __restrict__ W, ushort* __restrict__ Wb, int K) {
    int i = blockIdx.x * 256 + threadIdx.x;
    if (i >= K * 128) return;
    int k = i / 128, o = i % 128;
    int kg = k >> 3, e = k & 7;
    Wb[(((long)kg * 128 + o) * 8) + e] = f2bf(W[(long)o * K + k]);
}

// ---------------------------------------------------------------------------
// 3) Mean pool
// ---------------------------------------------------------------------------
__global__ void k_pool(const ushort* __restrict__ xT, const int* __restrict__ pn,
                       ushort* __restrict__ h1) {
    long t = (long)blockIdx.x * 256 + threadIdx.x;
    const long total = (long)B_SZ * NLO * 8;
    if (t >= total) return;
    int  cq = (int)(t & 7);
    long bn = t >> 3;
    int  n  = (int)(bn % NLO);
    int  b  = (int)(bn / NLO);
    float acc[8] = {};
#pragma unroll
    for (int j = 0; j < 7; ++j) {
        int idx = pn[n * 7 + j];
        short8 v = *(const short8*)&xT[((long)b * NHI + idx) * 64 + cq * 8];
#pragma unroll
        for (int e = 0; e < 8; ++e) acc[e] += bf2f((ushort)v[e]);
    }
    short8 o;
#pragma unroll
    for (int e = 0; e < 8; ++e) o[e] = (short)f2bf(acc[e] * (1.f / 7.f));
    *(short8*)&h1[bn * 64 + cq * 8] = o;
}

// Swizzled A-image index for 64-row tiles: (kg, nn) -> ushort offset.
// XOR of kg into nn keeps staging writes AND fragment reads conflict-free.
__device__ inline int aidx(int kg, int nn) {
    return (kg * 64 + (nn ^ ((kg & 7) << 1))) * 8;
}

// ---------------------------------------------------------------------------
// 4) MFMA one-ring conv. Block 64 nodes x 128 outs, 256 threads (4 waves,
//    wave tile 32x64). K-loop = one FULL neighbor row per step (7 steps):
//    conv2 touches each gathered 256B row once, 7 barriers total.
//    Depth-2 pipeline: loads for j+2 issued at step j; regs for j+1 written
//    to LDS at step j (a full step of latency coverage before the vmcnt).
//    B (weights) direct global->VGPR (L2-resident broadcast image).
//    LDS: A only, double-buffered swizzled image -> 4 blocks/CU.
// ---------------------------------------------------------------------------
template <int CIN>
__global__ __launch_bounds__(256, 4)
void k_conv_mfma(const ushort* __restrict__ src, const int* __restrict__ nbr,
                 const ushort* __restrict__ Wb, const float* __restrict__ bias,
                 ushort* __restrict__ out, float* __restrict__ part) {
    constexpr int KG = CIN / 8;        // k-groups per neighbor step (8 or 16)
    constexpr int CT = CIN / 32;       // 16B chunks per thread (2 or 4)
    __shared__ ushort Asm[2][KG * 64 * 8];   // 8KB (conv1) / 16KB (conv2) per buf
    __shared__ float  red[4][2][2];

    const int b     = blockIdx.y;
    const int n0    = blockIdx.x * 64;
    const int tid   = threadIdx.x;
    const int lane  = tid & 63;
    const int wave  = tid >> 6;          // 0..3
    const int wr    = wave >> 1, wc = wave & 1;
    const int l31   = lane & 31;
    const int khalf = lane >> 5;

    // A staging: 4 threads per node row, CT chunks of 16B each
    const int s_nn = tid >> 2;           // 0..63
    const int s_kq = tid & 3;
    const int r0 = min(n0 + s_nn, NLO - 1);
    int nb[7];
#pragma unroll
    for (int j = 0; j < 7; ++j) nb[j] = nbr[r0 * 7 + j];

    const long srcb = (long)b * NLO * CIN;
    f32x16 acc[2] = {};
    short8 aH[CT], aL[CT];

    // prologue: j=0 -> LDS[0]; j=1 -> aH
    {
        const ushort* p = &src[srcb + (long)nb[0] * CIN + s_kq * 8];
        short8 t[CT];
#pragma unroll
        for (int i = 0; i < CT; ++i) t[i] = *(const short8*)(p + i * 32);
#pragma unroll
        for (int i = 0; i < CT; ++i)
            *(short8*)&Asm[0][aidx(s_kq + 4 * i, s_nn)] = t[i];
        const ushort* p1 = &src[srcb + (long)nb[1] * CIN + s_kq * 8];
#pragma unroll
        for (int i = 0; i < CT; ++i) aH[i] = *(const short8*)(p1 + i * 32);
    }
    __syncthreads();

#pragma unroll
    for (int j = 0; j < 7; ++j) {
        const int cur = j & 1;
        // issue gather loads for j+2 (consumed by ds_write at step j+1)
        if (j + 2 < 7) {
            const ushort* p = &src[srcb + (long)nb[j + 2] * CIN + s_kq * 8];
#pragma unroll
            for (int i = 0; i < CT; ++i) aL[i] = *(const short8*)(p + i * 32);
        }
        // write A(j+1) (loaded at step j-1: full-step vmcnt coverage)
        if (j + 1 < 7) {
#pragma unroll
            for (int i = 0; i < CT; ++i)
                *(short8*)&Asm[cur ^ 1][aidx(s_kq + 4 * i, s_nn)] = aH[i];
        }
        // compute step j: B direct from global (L2-hot), A from LDS
        const ushort* wbj = &Wb[((long)j * KG * 128 + wc * 64 + l31) * 8];
#pragma unroll
        for (int kh = 0; kh < KG / 2; ++kh) {
            const int kg = 2 * kh + khalf;
            short8 A0 = *(const short8*)&Asm[cur][aidx(kg, wr * 32 + l31)];
            short8 B0 = *(const short8*)(wbj + (long)kg * 128 * 8);
            short8 B1 = *(const short8*)(wbj + (long)kg * 128 * 8 + 32 * 8);
            acc[0] = __builtin_amdgcn_mfma_f32_32x32x16_bf16(A0, B0, acc[0], 0, 0, 0);
            acc[1] = __builtin_amdgcn_mfma_f32_32x32x16_bf16(A0, B1, acc[1], 0, 0, 0);
        }
#pragma unroll
        for (int i = 0; i < CT; ++i) aH[i] = aL[i];
        __syncthreads();
    }

    // epilogue: bias, bf16 store, per-block GroupNorm partials
    float bia[2];
#pragma unroll
    for (int n = 0; n < 2; ++n) bia[n] = bias[wc * 64 + n * 32 + l31];
    float s[2] = {}, q[2] = {};
#pragma unroll
    for (int n = 0; n < 2; ++n)
#pragma unroll
        for (int r = 0; r < 16; ++r) {
            int crow = (r & 3) + 8 * (r >> 2) + 4 * khalf;
            int row  = n0 + wr * 32 + crow;
            float v  = acc[n][r] + bia[n];
            if (row < NLO) {
                out[((long)b * NLO + row) * 128 + wc * 64 + n * 32 + l31] = f2bf(v);
                s[n] += v; q[n] += v * v;
            }
        }
#pragma unroll
    for (int n = 0; n < 2; ++n)
#pragma unroll
        for (int off = 32; off > 0; off >>= 1) {
            s[n] += __shfl_down(s[n], off);
            q[n] += __shfl_down(q[n], off);
        }
    if (lane == 0) {
#pragma unroll
        for (int n = 0; n < 2; ++n) { red[wave][n][0] = s[n]; red[wave][n][1] = q[n]; }
    }
    __syncthreads();
    if (tid < 8) {
        int g = tid >> 1, isq = tid & 1;          // g = wc*2 + n
        int gwc = g >> 1, gn = g & 1;
        float v = red[gwc][gn][isq] + red[2 + gwc][gn][isq];
        part[(((long)b * gridDim.x + blockIdx.x) * 4 + g) * 2 + isq] = v;
    }
}

// ---------------------------------------------------------------------------
// 5) Finalize stats -> per (b,c) scale/shift. One block per (b,g).
// ---------------------------------------------------------------------------
__global__ void k_finalize(const float* __restrict__ part, int nblk,
                           const float* __restrict__ w, const float* __restrict__ bb,
                           float* __restrict__ scale, float* __restrict__ shift) {
    const int b = blockIdx.x >> 2, g = blockIdx.x & 3;
    const int tid = threadIdx.x;
    float s = 0.f, ss = 0.f;
    for (int k = tid; k < nblk; k += 256) {
        s  += part[(((long)b * nblk + k) * 4 + g) * 2 + 0];
        ss += part[(((long)b * nblk + k) * 4 + g) * 2 + 1];
    }
#pragma unroll
    for (int off = 32; off > 0; off >>= 1) {
        s += __shfl_down(s, off); ss += __shfl_down(ss, off);
    }
    __shared__ float red[8];
    __shared__ float fin[2];
    const int wave = tid >> 6, lane = tid & 63;
    if (lane == 0) { red[wave * 2] = s; red[wave * 2 + 1] = ss; }
    __syncthreads();
    if (tid == 0) {
        float as = red[0] + red[2] + red[4] + red[6];
        float aq = red[1] + red[3] + red[5] + red[7];
        const float cnt = 32.f * NLO;
        float mu  = as / cnt;
        float var = aq / cnt - mu * mu;
        fin[0] = mu; fin[1] = rsqrtf(var + EPS_GN);
    }
    __syncthreads();
    if (tid < 32) {
        int c = g * 32 + tid;
        float sc = fin[1] * w[c];
        scale[b * 128 + c] = sc;
        shift[b * 128 + c] = bb[c] - fin[0] * sc;
    }
}

// ---------------------------------------------------------------------------
// 6) Elementwise gn+leakyrelu: y (B,NLO,128) bf16 -> yp bf16
// ---------------------------------------------------------------------------
__global__ void k_gnapply(const ushort* __restrict__ y, const float* __restrict__ sc,
                          const float* __restrict__ sh, ushort* __restrict__ yp) {
    long t = (long)blockIdx.x * 256 + threadIdx.x;
    const long total = (long)B_SZ * NLO * 16;
    if (t >= total) return;
    int  c8 = (int)(t & 15);
    long bn = t >> 4;
    int  b  = (int)(bn / NLO);
    short8 v = *(const short8*)&y[bn * 128 + c8 * 8];
    short8 o;
#pragma unroll
    for (int e = 0; e < 8; ++e) {
        int c = c8 * 8 + e;
        float f = bf2f((ushort)v[e]) * sc[b * 128 + c] + sh[b * 128 + c];
        f = fmaxf(f, SLOPE * f);
        o[e] = (short)f2bf(f);
    }
    *(short8*)&yp[bn * 128 + c8 * 8] = o;
}

// ---------------------------------------------------------------------------
// 7) Output: gn2 + leakyrelu + transpose (B,N,128) bf16 -> (B,128,N) f32
// ---------------------------------------------------------------------------
__global__ void k_output(const ushort* __restrict__ y2, const float* __restrict__ scale,
                         const float* __restrict__ shift, float* __restrict__ out) {
    __shared__ float t[32][129];
    const int b   = blockIdx.y;
    const int n0  = blockIdx.x * 32;
    const int tid = threadIdx.x;
    const float* scb = &scale[b * 128];
    const float* shb = &shift[b * 128];
    const int c8 = (tid & 15) * 8;
#pragma unroll
    for (int r = 0; r < 2; ++r) {
        int nn = (tid >> 4) + r * 16;
        int n  = n0 + nn;
        if (n < NLO) {
            short8 v = *(const short8*)&y2[((long)b * NLO + n) * 128 + c8];
#pragma unroll
            for (int e = 0; e < 8; ++e) {
                int c = c8 + e;
                float f = bf2f((ushort)v[e]) * scb[c] + shb[c];
                t[nn][c] = fmaxf(f, SLOPE * f);
            }
        } else {
#pragma unroll
            for (int e = 0; e < 8; ++e) t[nn][c8 + e] = 0.f;
        }
    }
    __syncthreads();
    const int n4 = (tid & 7) * 4;
    const bool full = (n0 + 32) <= NLO;
#pragma unroll
    for (int r = 0; r < 4; ++r) {
        int c = (tid >> 3) + r * 32;
        long o = ((long)b * 128 + c) * NLO + n0 + n4;
        if (full) {
            float2 v0 = make_float2(t[n4][c], t[n4 + 1][c]);
            float2 v1 = make_float2(t[n4 + 2][c], t[n4 + 3][c]);
            *(float2*)&out[o]     = v0;
            *(float2*)&out[o + 2] = v1;
        } else {
            for (int e = 0; e < 4; ++e)
                if (n0 + n4 + e < NLO) out[o + e] = t[n4 + e][c];
        }
    }
}

// ---------------------------------------------------------------------------
// Launch
// ---------------------------------------------------------------------------
extern "C" void kernel_launch(void* const* d_in, const int* in_sizes, int n_in,
                              void* d_out, int out_size, void* d_ws, size_t ws_size,
                              hipStream_t stream) {
    const float* x   = (const float*)d_in[0];
    const int*   pn  = (const int*)d_in[1];
    const int*   cn  = (const int*)d_in[2];
    const float* W1  = (const float*)d_in[3];
    const float* b1  = (const float*)d_in[4];
    const float* g1w = (const float*)d_in[5];
    const float* g1b = (const float*)d_in[6];
    const float* W2  = (const float*)d_in[7];
    const float* b2  = (const float*)d_in[8];
    const float* g2w = (const float*)d_in[9];
    const float* g2b = (const float*)d_in[10];
    float* out = (float*)d_out;
    char*  base = (char*)d_ws;

    ushort* xT  = (ushort*)(base + 0);           // 83,887,104 B
    ushort* y1  = (ushort*)(base + 0);           // reuse (xT dead after pool)
    ushort* y1p = (ushort*)(base + 44000000);
    ushort* h1  = (ushort*)(base + 88000000);
    ushort* y2  = (ushort*)(base + 110000000);
    ushort* wb1 = (ushort*)(base + 152000000);
    ushort* wb2 = (ushort*)(base + 152200000);
    float*  p1  = (float*)(base + 152500000);
    float*  p2  = (float*)(base + 152600000);
    float*  sc1 = (float*)(base + 152700000);
    float*  sh1 = sc1 + 512;
    float*  sc2 = (float*)(base + 152710000);
    float*  sh2 = sc2 + 512;

    const int NBLK = (NLO + 63) / 64;  // 641 conv blocks per batch

    k_transpose_x<<<dim3((NHI + 63) / 64, B_SZ), 256, 0, stream>>>(x, xT);
    k_prep_w<<<(448 * 128 + 255) / 256, 256, 0, stream>>>(W1, wb1, 448);
    k_prep_w<<<(896 * 128 + 255) / 256, 256, 0, stream>>>(W2, wb2, 896);
    k_pool<<<(int)(((long)B_SZ * NLO * 8 + 255) / 256), 256, 0, stream>>>(xT, pn, h1);
    k_conv_mfma<64><<<dim3(NBLK, B_SZ), 256, 0, stream>>>(h1, cn, wb1, b1, y1, p1);
    k_finalize<<<16, 256, 0, stream>>>(p1, NBLK, g1w, g1b, sc1, sh1);
    k_gnapply<<<(int)(((long)B_SZ * NLO * 16 + 255) / 256), 256, 0, stream>>>(y1, sc1, sh1, y1p);
    k_conv_mfma<128><<<dim3(NBLK, B_SZ), 256, 0, stream>>>(y1p, cn, wb2, b2, y2, p2);
    k_finalize<<<16, 256, 0, stream>>>(p2, NBLK, g2w, g2b, sc2, sh2);
    k_output<<<dim3((NLO + 31) / 32, B_SZ), 256, 0, stream>>>(y2, sc2, sh2, out);
}